// Round 10
// baseline (64556.097 us; speedup 1.0000x reference)
//
#include <hip/hip_runtime.h>
#include <math.h>

#define TPB     128
#define NBATCH  64
#define SPB     16
#define NBLK    (NBATCH*SPB)       // 1024 blocks, 4/CU — co-residency guaranteed
#define SROWS   16
#define MM      256
#define AN      257
#define NITER   300
#define NIT1    (NITER+1)
#define SARR    (NBATCH*NIT1)      // ints per counter/flag array
#define RS      264
#define CO(k)   ((k) + ((k) >> 5))
#define DCH     256                // dot staging chunk (elements)

typedef float v4f __attribute__((ext_vector_type(4)));

// ---- contraction-proof IEEE fp32 ops (trajectory bit-identical to R8/R9).
__device__ __forceinline__ float mulf(float a, float b) {
  float d; asm("v_mul_f32 %0, %1, %2" : "=v"(d) : "v"(a), "v"(b)); return d;
}
__device__ __forceinline__ float addf(float a, float b) {
  float d; asm("v_add_f32 %0, %1, %2" : "=v"(d) : "v"(a), "v"(b)); return d;
}
__device__ __forceinline__ float subf(float a, float b) {
  float d; asm("v_sub_f32 %0, %1, %2" : "=v"(d) : "v"(a), "v"(b)); return d;
}
__device__ __forceinline__ float fmacf(float acc, float x, float y) {
  asm("v_fmac_f32 %0, %1, %2" : "+v"(acc) : "v"(x), "v"(y)); return acc;
}

// ---- coherent transport: per-access LLC-coherent, cache-bypassing, VECTORIZED.
// 16B/lane wave-contiguous -> fully covered sectors, no write amplification.
__device__ __forceinline__ v4f ld4c(const float* p) {
  v4f r;
  asm volatile("global_load_dwordx4 %0, %1, off sc0 sc1" : "=v"(r) : "v"(p) : "memory");
  return r;
}
__device__ __forceinline__ void st4c(float* p, v4f v) {
  asm volatile("global_store_dwordx4 %0, %1, off sc0 sc1" :: "v"(p), "v"(v) : "memory");
}
__device__ __forceinline__ void vmdrain()  { asm volatile("s_waitcnt vmcnt(0)" ::: "memory"); }
__device__ __forceinline__ void lgkmdrain(){ asm volatile("s_waitcnt lgkmcnt(0)" ::: "memory"); }
__device__ __forceinline__ void drain_all(){ asm volatile("s_waitcnt vmcnt(0) lgkmcnt(0)" ::: "memory"); }

#define ALD_F(p)    __hip_atomic_load((p),  __ATOMIC_RELAXED, __HIP_MEMORY_SCOPE_AGENT)
#define AST_F(p,v)  __hip_atomic_store((p), (v), __ATOMIC_RELAXED, __HIP_MEMORY_SCOPE_AGENT)
#define ALD_I(p)    __hip_atomic_load((p),  __ATOMIC_RELAXED, __HIP_MEMORY_SCOPE_AGENT)

__global__ void init_ws_kernel(int* __restrict__ z, int n) {
  int i = blockIdx.x * blockDim.x + threadIdx.x;
  if (i < n) z[i] = 0;
}

__device__ __forceinline__ void waitEq(int* p, int target) {
  int tries = 0;
  while (ALD_I(p) < target) {
    __builtin_amdgcn_s_sleep(4);
    if (++tries > (1 << 22)) break;   // hang-safety valve (never expected)
  }
}

// Order-exact dot (bit-identical to R8/R9 dot32): slot l sums elements g≡l
// (mod 32) ascending via one 2048-long FMA chain; identical combine tree.
// Transport: 64-lane ld4c -> LDS chunk -> lanes 0..31 chain. w = tid (0..63).
__device__ float dot32s(const float* __restrict__ X, const float* __restrict__ Y,
                        float* __restrict__ sX, float* __restrict__ sY, int w) {
  v4f xv, yv, xn, yn;
  xv = ld4c(X + 4 * w);
  yv = ld4c(Y + 4 * w);
  float acc = 0.0f;
  #pragma unroll 1
  for (int c = 0; c < 256; ++c) {
    vmdrain();                                 // xv,yv arrived
    *(v4f*)&sX[4 * w] = xv;                    // ds_write_b128 (16B-aligned)
    *(v4f*)&sY[4 * w] = yv;
    if (c < 255) {                             // prefetch next chunk
      xn = ld4c(X + (size_t)(c + 1) * DCH + 4 * w);
      yn = ld4c(Y + (size_t)(c + 1) * DCH + 4 * w);
    }
    lgkmdrain();                               // staging visible wave-wide
    if (w < 32) {
      #pragma unroll
      for (int t = 0; t < 8; ++t)
        acc = fmacf(acc, sX[t * 32 + w], sY[t * 32 + w]);
    }
    lgkmdrain();                               // reads done before next overwrite
    xv = xn; yv = yn;
  }
  float d[32];
  #pragma unroll
  for (int o = 0; o < 32; ++o) d[o] = __shfl(acc, o, 64);
  float C[8];
  #pragma unroll
  for (int l = 0; l < 8; ++l)
    C[l] = addf(addf(d[l], d[8 + l]), addf(d[16 + l], d[24 + l]));
  float D[4];
  #pragma unroll
  for (int l = 0; l < 4; ++l) D[l] = addf(C[l], C[l + 4]);
  return addf(addf(D[0], D[1]), addf(D[2], D[3]));
}

__launch_bounds__(TPB, 2)
__global__ void cg_kernel(const float* __restrict__ alpha,
                          const float* __restrict__ frhs,
                          float* __restrict__ out,
                          int* __restrict__ Z,
                          float* __restrict__ av,
                          float* __restrict__ bv,
                          float* __restrict__ halo,
                          float* __restrict__ pbuf,
                          float* __restrict__ apbuf,
                          float* __restrict__ rbuf)
{
  __shared__ float sP[(SROWS + 2) * RS];
  __shared__ __align__(16) float sDot[2 * DCH];
  float* sX = sDot;
  float* sY = sDot + DCH;

  int* cntP  = Z + 0 * SARR;
  int* cntA  = Z + 1 * SARR;
  int* cntB  = Z + 2 * SARR;
  int* flagA = Z + 3 * SARR;
  int* flagB = Z + 4 * SARR;

  const int tid  = threadIdx.x;
  const int bx   = blockIdx.x;
  const int b    = bx >> 4;
  const int s    = bx & 15;
  const int js   = s * SROWS;
  const int jloc = tid >> 3;
  const int k0   = (tid & 7) << 5;
  const int jg   = js + jloc;
  const int rowb = (jloc + 1) * RS;
  const size_t gbase = (size_t)b * (MM * MM) + (size_t)jg * MM + k0;

  // ---- coefficients once, reference fp32 rounding order (bit-identical)
  float kl[32], kr[32], kb[32], kt[32], dg[32];
  {
    const float* r0 = alpha + (size_t)b * (AN * AN) + (size_t)jg * AN + k0;
    const float* r1 = r0 + AN;
    float a0[33], a1[33];
    #pragma unroll
    for (int i = 0; i < 33; ++i) { a0[i] = r0[i]; a1[i] = r1[i]; }
    #pragma unroll
    for (int i = 0; i < 32; ++i) {
      const int kg = k0 + i;
      float vkl = expf(0.5f * (a0[i] + a0[i + 1]));
      float vkr = (jg < MM - 1) ? expf(0.5f * (a1[i] + a1[i + 1])) : 0.0f;
      float vkb = (kg > 0)      ? expf(0.5f * (a0[i] + a1[i]))     : 0.0f;
      float vkt = (kg < MM - 1) ? expf(0.5f * (a0[i + 1] + a1[i + 1])) : 0.0f;
      float d = ((vkl + vkr) + vkb) + vkt;
      if (jg == 0) d += vkl;
      kl[i] = vkl; kr[i] = vkr; kb[i] = vkb; kt[i] = vkt; dg[i] = d;
    }
  }

  float uu[32], rr[32], pp[32], Ap[32];
  {
    const float* fB = frhs + (size_t)jg * MM + k0;
    #pragma unroll
    for (int i = 0; i < 32; ++i) {
      float v = fB[i];
      uu[i] = 0.0f; rr[i] = v; pp[i] = v;
      sP[rowb + CO(k0 + i)] = v;
    }
    #pragma unroll
    for (int q = 0; q < 8; ++q) {
      v4f pv; pv[0] = pp[4*q]; pv[1] = pp[4*q+1]; pv[2] = pp[4*q+2]; pv[3] = pp[4*q+3];
      st4c(&pbuf[gbase + 4 * q], pv);
      st4c(&rbuf[gbase + 4 * q], pv);
    }
  }
  float* myhalo = halo + (size_t)bx * 512;
  if (jloc == 0) {
    #pragma unroll
    for (int q = 0; q < 8; ++q) {
      v4f hv; hv[0] = pp[4*q]; hv[1] = pp[4*q+1]; hv[2] = pp[4*q+2]; hv[3] = pp[4*q+3];
      st4c(&myhalo[k0 + 4 * q], hv);
    }
  }
  if (jloc == SROWS - 1) {
    #pragma unroll
    for (int q = 0; q < 8; ++q) {
      v4f hv; hv[0] = pp[4*q]; hv[1] = pp[4*q+1]; hv[2] = pp[4*q+2]; hv[3] = pp[4*q+3];
      st4c(&myhalo[256 + k0 + 4 * q], hv);
    }
  }
  drain_all();
  __syncthreads();
  if (tid == 0)
    __hip_atomic_fetch_add(&cntP[b * NIT1 + 0], 1, __ATOMIC_RELAXED,
                           __HIP_MEMORY_SCOPE_AGENT);

  float gamma_red = 0.0f;   // live in wave 0 of s==0

  for (int it = 1; it <= NITER; ++it) {
    // ---- phase A: wait p ready, stage halos, stencil, publish Ap
    if (tid == 0) waitEq(&cntP[b * NIT1 + it - 1], SPB);
    __syncthreads();
    if (jloc == 0) {
      if (s > 0) {
        float* nh = halo + (size_t)(bx - 1) * 512 + 256;
        v4f hv[8];
        #pragma unroll
        for (int q = 0; q < 8; ++q) hv[q] = ld4c(&nh[k0 + 4 * q]);
        vmdrain();
        #pragma unroll
        for (int q = 0; q < 8; ++q) {
          sP[CO(k0 + 4*q)]     = hv[q][0];
          sP[CO(k0 + 4*q + 1)] = hv[q][1];
          sP[CO(k0 + 4*q + 2)] = hv[q][2];
          sP[CO(k0 + 4*q + 3)] = hv[q][3];
        }
      } else {
        #pragma unroll
        for (int i = 0; i < 32; ++i) sP[CO(k0 + i)] = 0.0f;
      }
    }
    if (jloc == SROWS - 1) {
      if (s < SPB - 1) {
        float* nh = halo + (size_t)(bx + 1) * 512;
        v4f hv[8];
        #pragma unroll
        for (int q = 0; q < 8; ++q) hv[q] = ld4c(&nh[k0 + 4 * q]);
        vmdrain();
        #pragma unroll
        for (int q = 0; q < 8; ++q) {
          sP[(SROWS + 1) * RS + CO(k0 + 4*q)]     = hv[q][0];
          sP[(SROWS + 1) * RS + CO(k0 + 4*q + 1)] = hv[q][1];
          sP[(SROWS + 1) * RS + CO(k0 + 4*q + 2)] = hv[q][2];
          sP[(SROWS + 1) * RS + CO(k0 + 4*q + 3)] = hv[q][3];
        }
      } else {
        #pragma unroll
        for (int i = 0; i < 32; ++i) sP[(SROWS + 1) * RS + CO(k0 + i)] = 0.0f;
      }
    }
    __syncthreads();

    {
      v4f apv;
      #pragma unroll
      for (int i = 0; i < 32; ++i) {
        const int kg = k0 + i;
        float pc = pp[i];
        float pd = sP[rowb - RS + CO(kg)];
        float pu = sP[rowb + RS + CO(kg)];
        float pl = (i > 0) ? pp[i - 1]
                           : ((k0 > 0) ? sP[rowb + CO(k0 - 1)] : 0.0f);
        float pr = (i < 31) ? pp[i + 1]
                            : ((kg < MM - 1) ? sP[rowb + CO(k0 + 32)] : 0.0f);
        float t = mulf(dg[i], pc);
        t = subf(t, mulf(kl[i], pd));
        t = subf(t, mulf(kr[i], pu));
        t = subf(t, mulf(kb[i], pl));
        t = subf(t, mulf(kt[i], pr));
        float ap = mulf(65536.0f, t);
        Ap[i] = ap;
        apv[i & 3] = ap;
        if ((i & 3) == 3) st4c(&apbuf[gbase + (i - 3)], apv);
      }
    }
    drain_all();
    __syncthreads();
    if (tid == 0)
      __hip_atomic_fetch_add(&cntA[b * NIT1 + it], 1, __ATOMIC_RELAXED,
                             __HIP_MEMORY_SCOPE_AGENT);

    // ---- reducer: alpha = gamma / (p.Ap)
    if (s == 0 && tid < 64) {
      waitEq(&cntA[b * NIT1 + it], SPB);
      const float* Pb  = pbuf  + (size_t)b * (MM * MM);
      const float* APb = apbuf + (size_t)b * (MM * MM);
      const float* Rb  = rbuf  + (size_t)b * (MM * MM);
      if (it == 1) gamma_red = dot32s(Rb, Rb, sX, sY, tid);
      float pap = dot32s(Pb, APb, sX, sY, tid);
      if (tid == 0) {
        AST_F(&av[b * NIT1 + it], gamma_red / pap);
        vmdrain();
        __hip_atomic_store(&flagA[b * NIT1 + it], 1, __ATOMIC_RELAXED,
                           __HIP_MEMORY_SCOPE_AGENT);
      }
    }

    // ---- phase B: x += a p ; r -= a Ap ; publish r
    if (tid == 0) waitEq(&flagA[b * NIT1 + it], 1);
    __syncthreads();
    float alf = ALD_F(&av[b * NIT1 + it]);
    {
      v4f rv;
      #pragma unroll
      for (int i = 0; i < 32; ++i) {
        uu[i] = addf(uu[i], mulf(alf, pp[i]));
        rr[i] = subf(rr[i], mulf(alf, Ap[i]));
        rv[i & 3] = rr[i];
        if ((i & 3) == 3) st4c(&rbuf[gbase + (i - 3)], rv);
      }
    }
    drain_all();
    __syncthreads();
    if (tid == 0)
      __hip_atomic_fetch_add(&cntB[b * NIT1 + it], 1, __ATOMIC_RELAXED,
                             __HIP_MEMORY_SCOPE_AGENT);

    // ---- reducer: beta = gamma'/gamma
    if (s == 0 && tid < 64) {
      waitEq(&cntB[b * NIT1 + it], SPB);
      const float* Rb = rbuf + (size_t)b * (MM * MM);
      float g2 = dot32s(Rb, Rb, sX, sY, tid);
      float bet = g2 / gamma_red;
      gamma_red = g2;
      if (tid == 0) {
        AST_F(&bv[b * NIT1 + it], bet);
        vmdrain();
        __hip_atomic_store(&flagB[b * NIT1 + it], 1, __ATOMIC_RELAXED,
                           __HIP_MEMORY_SCOPE_AGENT);
      }
    }

    // ---- phase C: p = r + b p ; publish p + halos
    if (tid == 0) waitEq(&flagB[b * NIT1 + it], 1);
    __syncthreads();
    float bet = ALD_F(&bv[b * NIT1 + it]);
    {
      v4f pv;
      #pragma unroll
      for (int i = 0; i < 32; ++i) {
        float pn = addf(rr[i], mulf(bet, pp[i]));
        pp[i] = pn;
        sP[rowb + CO(k0 + i)] = pn;
        pv[i & 3] = pn;
        if ((i & 3) == 3) st4c(&pbuf[gbase + (i - 3)], pv);
      }
    }
    if (jloc == 0) {
      #pragma unroll
      for (int q = 0; q < 8; ++q) {
        v4f hv; hv[0] = pp[4*q]; hv[1] = pp[4*q+1]; hv[2] = pp[4*q+2]; hv[3] = pp[4*q+3];
        st4c(&myhalo[k0 + 4 * q], hv);
      }
    }
    if (jloc == SROWS - 1) {
      #pragma unroll
      for (int q = 0; q < 8; ++q) {
        v4f hv; hv[0] = pp[4*q]; hv[1] = pp[4*q+1]; hv[2] = pp[4*q+2]; hv[3] = pp[4*q+3];
        st4c(&myhalo[256 + k0 + 4 * q], hv);
      }
    }
    drain_all();
    __syncthreads();
    if (tid == 0)
      __hip_atomic_fetch_add(&cntP[b * NIT1 + it], 1, __ATOMIC_RELAXED,
                             __HIP_MEMORY_SCOPE_AGENT);
  }

  float* oB = out + gbase;
  #pragma unroll
  for (int i = 0; i < 32; ++i) oB[i] = uu[i];
}

extern "C" void kernel_launch(void* const* d_in, const int* in_sizes, int n_in,
                              void* d_out, int out_size, void* d_ws, size_t ws_size,
                              hipStream_t stream) {
  const float* alpha = (const float*)d_in[0];   // (64, 257, 257) fp32
  const float* frhs  = (const float*)d_in[1];   // (256, 256) fp32
  float* out = (float*)d_out;                   // (64, 256, 256) fp32

  char* ws = (char*)d_ws;
  int*   Z    = (int*)ws;                               // 5 int arrays [64][301]
  float* av   = (float*)(ws + (size_t)5 * SARR * 4);
  float* bv   = (float*)(ws + (size_t)6 * SARR * 4);
  size_t ZR   = ((size_t)7 * SARR * 4 + 4095) & ~(size_t)4095;
  float* halo  = (float*)(ws + ZR);                     // 2 MB
  float* pbuf  = (float*)(ws + ZR + (size_t)NBLK * 512 * 4);
  float* apbuf = pbuf  + (size_t)NBATCH * MM * MM;      // 16 MB each
  float* rbuf  = apbuf + (size_t)NBATCH * MM * MM;

  int nz = 5 * SARR;
  hipLaunchKernelGGL(init_ws_kernel, dim3((nz + 255) / 256), dim3(256), 0, stream,
                     Z, nz);
  hipLaunchKernelGGL(cg_kernel, dim3(NBLK), dim3(TPB), 0, stream,
                     alpha, frhs, out, Z, av, bv, halo, pbuf, apbuf, rbuf);
}

// Round 11
// 51931.891 us; speedup vs baseline: 1.2431x; 1.2431x over previous
//
#include <hip/hip_runtime.h>
#include <math.h>

#define TPB     128
#define NBATCH  64
#define SPB     16
#define NBLK    (NBATCH*SPB)       // 1024 blocks, 4/CU — co-residency guaranteed
#define SROWS   16
#define MM      256
#define AN      257
#define NITER   300
#define NIT1    (NITER+1)
#define SARR    (NBATCH*NIT1)      // ints per counter/flag array
#define RS      264
#define CO(k)   ((k) + ((k) >> 5))
#define DCH     256                // dot staging chunk (elements)

typedef float v4f __attribute__((ext_vector_type(4)));

// ---- contraction-proof IEEE fp32 ops (trajectory bit-identical to R8/R9/R10).
__device__ __forceinline__ float mulf(float a, float b) {
  float d; asm("v_mul_f32 %0, %1, %2" : "=v"(d) : "v"(a), "v"(b)); return d;
}
__device__ __forceinline__ float addf(float a, float b) {
  float d; asm("v_add_f32 %0, %1, %2" : "=v"(d) : "v"(a), "v"(b)); return d;
}
__device__ __forceinline__ float subf(float a, float b) {
  float d; asm("v_sub_f32 %0, %1, %2" : "=v"(d) : "v"(a), "v"(b)); return d;
}
__device__ __forceinline__ float fmacf(float acc, float x, float y) {
  asm("v_fmac_f32 %0, %1, %2" : "+v"(acc) : "v"(x), "v"(y)); return acc;
}

// ---- coherent transport: per-access LLC/HBM-coherent, cache-bypassing, vectorized.
__device__ __forceinline__ v4f ld4c(const float* p) {
  v4f r;
  asm volatile("global_load_dwordx4 %0, %1, off sc0 sc1" : "=v"(r) : "v"(p) : "memory");
  return r;
}
__device__ __forceinline__ void st4c(float* p, v4f v) {
  asm volatile("global_store_dwordx4 %0, %1, off sc0 sc1" :: "v"(p), "v"(v) : "memory");
}
__device__ __forceinline__ void vmdrain()  { asm volatile("s_waitcnt vmcnt(0)" ::: "memory"); }
__device__ __forceinline__ void drain_all(){ asm volatile("s_waitcnt vmcnt(0) lgkmcnt(0)" ::: "memory"); }

#define ALD_F(p)    __hip_atomic_load((p),  __ATOMIC_RELAXED, __HIP_MEMORY_SCOPE_AGENT)
#define AST_F(p,v)  __hip_atomic_store((p), (v), __ATOMIC_RELAXED, __HIP_MEMORY_SCOPE_AGENT)
#define ALD_I(p)    __hip_atomic_load((p),  __ATOMIC_RELAXED, __HIP_MEMORY_SCOPE_AGENT)

__global__ void init_ws_kernel(int* __restrict__ z, int n) {
  int i = blockIdx.x * blockDim.x + threadIdx.x;
  if (i < n) z[i] = 0;
}

__device__ __forceinline__ void waitEq(int* p, int target) {
  int tries = 0;
  while (ALD_I(p) < target) {
    __builtin_amdgcn_s_sleep(2);
    if (++tries > (1 << 22)) break;   // hang-safety valve (never expected)
  }
}

// Order-exact dot, bit-identical chain to R8/R9/R10: slot l (lanes 0..31) sums
// elements g≡l (mod 32) in ascending g via one 2048-long single-rounded FMA
// chain; identical combine tree. Transport: 8-chunk register ring of in-flight
// ld4c (16 outstanding/lane), consume oldest at vmcnt(14), stage via 2KB LDS.
// HBM latency (~900cyc) amortized 8x -> per-chunk ~120cyc.
#define DOT_FMA8 \
    if (w < 32) { \
      acc = fmacf(acc, sX[0*32+w], sY[0*32+w]); \
      acc = fmacf(acc, sX[1*32+w], sY[1*32+w]); \
      acc = fmacf(acc, sX[2*32+w], sY[2*32+w]); \
      acc = fmacf(acc, sX[3*32+w], sY[3*32+w]); \
      acc = fmacf(acc, sX[4*32+w], sY[4*32+w]); \
      acc = fmacf(acc, sX[5*32+w], sY[5*32+w]); \
      acc = fmacf(acc, sX[6*32+w], sY[6*32+w]); \
      acc = fmacf(acc, sX[7*32+w], sY[7*32+w]); \
    }

#define DOT_STEP(D) { \
    asm volatile("s_waitcnt vmcnt(14)" ::: "memory"); \
    *(v4f*)&sX[4 * w] = xq[D]; \
    *(v4f*)&sY[4 * w] = yq[D]; \
    asm volatile("s_waitcnt lgkmcnt(0)" ::: "memory"); \
    xq[D] = ld4c(xp + (size_t)(c0 + (D) + 8) * DCH); \
    yq[D] = ld4c(yp + (size_t)(c0 + (D) + 8) * DCH); \
    DOT_FMA8 \
    asm volatile("s_waitcnt lgkmcnt(0)" ::: "memory"); }

#define DOT_TAIL(D, VM) { \
    asm volatile("s_waitcnt vmcnt(" #VM ")" ::: "memory"); \
    *(v4f*)&sX[4 * w] = xq[D]; \
    *(v4f*)&sY[4 * w] = yq[D]; \
    asm volatile("s_waitcnt lgkmcnt(0)" ::: "memory"); \
    DOT_FMA8 \
    asm volatile("s_waitcnt lgkmcnt(0)" ::: "memory"); }

__device__ float dot32p(const float* __restrict__ X, const float* __restrict__ Y,
                        float* __restrict__ sX, float* __restrict__ sY, int w) {
  const float* xp = X + 4 * w;
  const float* yp = Y + 4 * w;
  v4f xq[8], yq[8];
  #pragma unroll
  for (int d = 0; d < 8; ++d) {            // prologue: chunks 0..7 in flight
    xq[d] = ld4c(xp + (size_t)d * DCH);
    yq[d] = ld4c(yp + (size_t)d * DCH);
  }
  float acc = 0.0f;
  #pragma unroll 1
  for (int g = 0; g < 31; ++g) {           // chunks 0..247, reissue +8 ahead
    const int c0 = g * 8;
    DOT_STEP(0) DOT_STEP(1) DOT_STEP(2) DOT_STEP(3)
    DOT_STEP(4) DOT_STEP(5) DOT_STEP(6) DOT_STEP(7)
  }
  DOT_TAIL(0, 14) DOT_TAIL(1, 12) DOT_TAIL(2, 10) DOT_TAIL(3, 8)
  DOT_TAIL(4, 6)  DOT_TAIL(5, 4)  DOT_TAIL(6, 2)  DOT_TAIL(7, 0)

  float d[32];
  #pragma unroll
  for (int o = 0; o < 32; ++o) d[o] = __shfl(acc, o, 64);
  float C[8];
  #pragma unroll
  for (int l = 0; l < 8; ++l)
    C[l] = addf(addf(d[l], d[8 + l]), addf(d[16 + l], d[24 + l]));
  float D[4];
  #pragma unroll
  for (int l = 0; l < 4; ++l) D[l] = addf(C[l], C[l + 4]);
  return addf(addf(D[0], D[1]), addf(D[2], D[3]));
}

__launch_bounds__(TPB, 2)
__global__ void cg_kernel(const float* __restrict__ alpha,
                          const float* __restrict__ frhs,
                          float* __restrict__ out,
                          int* __restrict__ Z,
                          float* __restrict__ av,
                          float* __restrict__ bv,
                          float* __restrict__ halo,
                          float* __restrict__ pbuf,
                          float* __restrict__ apbuf,
                          float* __restrict__ rbuf)
{
  __shared__ float sP[(SROWS + 2) * RS];
  __shared__ __align__(16) float sDot[2 * DCH];
  float* sX = sDot;
  float* sY = sDot + DCH;

  int* cntP  = Z + 0 * SARR;
  int* cntA  = Z + 1 * SARR;
  int* cntB  = Z + 2 * SARR;
  int* flagA = Z + 3 * SARR;
  int* flagB = Z + 4 * SARR;

  const int tid  = threadIdx.x;
  const int bx   = blockIdx.x;
  const int b    = bx >> 4;
  const int s    = bx & 15;
  const int js   = s * SROWS;
  const int jloc = tid >> 3;
  const int k0   = (tid & 7) << 5;
  const int jg   = js + jloc;
  const int rowb = (jloc + 1) * RS;
  const size_t gbase = (size_t)b * (MM * MM) + (size_t)jg * MM + k0;

  // ---- coefficients once, reference fp32 rounding order (bit-identical)
  float kl[32], kr[32], kb[32], kt[32], dg[32];
  {
    const float* r0 = alpha + (size_t)b * (AN * AN) + (size_t)jg * AN + k0;
    const float* r1 = r0 + AN;
    float a0[33], a1[33];
    #pragma unroll
    for (int i = 0; i < 33; ++i) { a0[i] = r0[i]; a1[i] = r1[i]; }
    #pragma unroll
    for (int i = 0; i < 32; ++i) {
      const int kg = k0 + i;
      float vkl = expf(0.5f * (a0[i] + a0[i + 1]));
      float vkr = (jg < MM - 1) ? expf(0.5f * (a1[i] + a1[i + 1])) : 0.0f;
      float vkb = (kg > 0)      ? expf(0.5f * (a0[i] + a1[i]))     : 0.0f;
      float vkt = (kg < MM - 1) ? expf(0.5f * (a0[i + 1] + a1[i + 1])) : 0.0f;
      float d = ((vkl + vkr) + vkb) + vkt;
      if (jg == 0) d += vkl;
      kl[i] = vkl; kr[i] = vkr; kb[i] = vkb; kt[i] = vkt; dg[i] = d;
    }
  }

  float uu[32], rr[32], pp[32], Ap[32];
  {
    const float* fB = frhs + (size_t)jg * MM + k0;
    #pragma unroll
    for (int i = 0; i < 32; ++i) {
      float v = fB[i];
      uu[i] = 0.0f; rr[i] = v; pp[i] = v;
      sP[rowb + CO(k0 + i)] = v;
    }
    #pragma unroll
    for (int q = 0; q < 8; ++q) {
      v4f pv; pv[0] = pp[4*q]; pv[1] = pp[4*q+1]; pv[2] = pp[4*q+2]; pv[3] = pp[4*q+3];
      st4c(&pbuf[gbase + 4 * q], pv);
      st4c(&rbuf[gbase + 4 * q], pv);
    }
  }
  float* myhalo = halo + (size_t)bx * 512;
  if (jloc == 0) {
    #pragma unroll
    for (int q = 0; q < 8; ++q) {
      v4f hv; hv[0] = pp[4*q]; hv[1] = pp[4*q+1]; hv[2] = pp[4*q+2]; hv[3] = pp[4*q+3];
      st4c(&myhalo[k0 + 4 * q], hv);
    }
  }
  if (jloc == SROWS - 1) {
    #pragma unroll
    for (int q = 0; q < 8; ++q) {
      v4f hv; hv[0] = pp[4*q]; hv[1] = pp[4*q+1]; hv[2] = pp[4*q+2]; hv[3] = pp[4*q+3];
      st4c(&myhalo[256 + k0 + 4 * q], hv);
    }
  }
  drain_all();
  __syncthreads();
  if (tid == 0)
    __hip_atomic_fetch_add(&cntP[b * NIT1 + 0], 1, __ATOMIC_RELAXED,
                           __HIP_MEMORY_SCOPE_AGENT);

  float gamma_red = 0.0f;   // live in wave 0 of s==0

  for (int it = 1; it <= NITER; ++it) {
    // ---- phase A: wait p ready, stage halos, stencil, publish Ap
    if (tid == 0) waitEq(&cntP[b * NIT1 + it - 1], SPB);
    __syncthreads();
    if (jloc == 0) {
      if (s > 0) {
        float* nh = halo + (size_t)(bx - 1) * 512 + 256;
        v4f hv[8];
        #pragma unroll
        for (int q = 0; q < 8; ++q) hv[q] = ld4c(&nh[k0 + 4 * q]);
        vmdrain();
        #pragma unroll
        for (int q = 0; q < 8; ++q) {
          sP[CO(k0 + 4*q)]     = hv[q][0];
          sP[CO(k0 + 4*q + 1)] = hv[q][1];
          sP[CO(k0 + 4*q + 2)] = hv[q][2];
          sP[CO(k0 + 4*q + 3)] = hv[q][3];
        }
      } else {
        #pragma unroll
        for (int i = 0; i < 32; ++i) sP[CO(k0 + i)] = 0.0f;
      }
    }
    if (jloc == SROWS - 1) {
      if (s < SPB - 1) {
        float* nh = halo + (size_t)(bx + 1) * 512;
        v4f hv[8];
        #pragma unroll
        for (int q = 0; q < 8; ++q) hv[q] = ld4c(&nh[k0 + 4 * q]);
        vmdrain();
        #pragma unroll
        for (int q = 0; q < 8; ++q) {
          sP[(SROWS + 1) * RS + CO(k0 + 4*q)]     = hv[q][0];
          sP[(SROWS + 1) * RS + CO(k0 + 4*q + 1)] = hv[q][1];
          sP[(SROWS + 1) * RS + CO(k0 + 4*q + 2)] = hv[q][2];
          sP[(SROWS + 1) * RS + CO(k0 + 4*q + 3)] = hv[q][3];
        }
      } else {
        #pragma unroll
        for (int i = 0; i < 32; ++i) sP[(SROWS + 1) * RS + CO(k0 + i)] = 0.0f;
      }
    }
    __syncthreads();

    {
      v4f apv;
      #pragma unroll
      for (int i = 0; i < 32; ++i) {
        const int kg = k0 + i;
        float pc = pp[i];
        float pd = sP[rowb - RS + CO(kg)];
        float pu = sP[rowb + RS + CO(kg)];
        float pl = (i > 0) ? pp[i - 1]
                           : ((k0 > 0) ? sP[rowb + CO(k0 - 1)] : 0.0f);
        float pr = (i < 31) ? pp[i + 1]
                            : ((kg < MM - 1) ? sP[rowb + CO(k0 + 32)] : 0.0f);
        float t = mulf(dg[i], pc);
        t = subf(t, mulf(kl[i], pd));
        t = subf(t, mulf(kr[i], pu));
        t = subf(t, mulf(kb[i], pl));
        t = subf(t, mulf(kt[i], pr));
        float ap = mulf(65536.0f, t);
        Ap[i] = ap;
        apv[i & 3] = ap;
        if ((i & 3) == 3) st4c(&apbuf[gbase + (i - 3)], apv);
      }
    }
    drain_all();
    __syncthreads();
    if (tid == 0)
      __hip_atomic_fetch_add(&cntA[b * NIT1 + it], 1, __ATOMIC_RELAXED,
                             __HIP_MEMORY_SCOPE_AGENT);

    // ---- reducer: alpha = gamma / (p.Ap)
    if (s == 0 && tid < 64) {
      waitEq(&cntA[b * NIT1 + it], SPB);
      const float* Pb  = pbuf  + (size_t)b * (MM * MM);
      const float* APb = apbuf + (size_t)b * (MM * MM);
      const float* Rb  = rbuf  + (size_t)b * (MM * MM);
      if (it == 1) gamma_red = dot32p(Rb, Rb, sX, sY, tid);
      float pap = dot32p(Pb, APb, sX, sY, tid);
      if (tid == 0) {
        AST_F(&av[b * NIT1 + it], gamma_red / pap);
        vmdrain();
        __hip_atomic_store(&flagA[b * NIT1 + it], 1, __ATOMIC_RELAXED,
                           __HIP_MEMORY_SCOPE_AGENT);
      }
    }

    // ---- phase B: x += a p ; r -= a Ap ; publish r
    if (tid == 0) waitEq(&flagA[b * NIT1 + it], 1);
    __syncthreads();
    float alf = ALD_F(&av[b * NIT1 + it]);
    {
      v4f rv;
      #pragma unroll
      for (int i = 0; i < 32; ++i) {
        uu[i] = addf(uu[i], mulf(alf, pp[i]));
        rr[i] = subf(rr[i], mulf(alf, Ap[i]));
        rv[i & 3] = rr[i];
        if ((i & 3) == 3) st4c(&rbuf[gbase + (i - 3)], rv);
      }
    }
    drain_all();
    __syncthreads();
    if (tid == 0)
      __hip_atomic_fetch_add(&cntB[b * NIT1 + it], 1, __ATOMIC_RELAXED,
                             __HIP_MEMORY_SCOPE_AGENT);

    // ---- reducer: beta = gamma'/gamma
    if (s == 0 && tid < 64) {
      waitEq(&cntB[b * NIT1 + it], SPB);
      const float* Rb = rbuf + (size_t)b * (MM * MM);
      float g2 = dot32p(Rb, Rb, sX, sY, tid);
      float bet = g2 / gamma_red;
      gamma_red = g2;
      if (tid == 0) {
        AST_F(&bv[b * NIT1 + it], bet);
        vmdrain();
        __hip_atomic_store(&flagB[b * NIT1 + it], 1, __ATOMIC_RELAXED,
                           __HIP_MEMORY_SCOPE_AGENT);
      }
    }

    // ---- phase C: p = r + b p ; publish p + halos
    if (tid == 0) waitEq(&flagB[b * NIT1 + it], 1);
    __syncthreads();
    float bet = ALD_F(&bv[b * NIT1 + it]);
    {
      v4f pv;
      #pragma unroll
      for (int i = 0; i < 32; ++i) {
        float pn = addf(rr[i], mulf(bet, pp[i]));
        pp[i] = pn;
        sP[rowb + CO(k0 + i)] = pn;
        pv[i & 3] = pn;
        if ((i & 3) == 3) st4c(&pbuf[gbase + (i - 3)], pv);
      }
    }
    if (jloc == 0) {
      #pragma unroll
      for (int q = 0; q < 8; ++q) {
        v4f hv; hv[0] = pp[4*q]; hv[1] = pp[4*q+1]; hv[2] = pp[4*q+2]; hv[3] = pp[4*q+3];
        st4c(&myhalo[k0 + 4 * q], hv);
      }
    }
    if (jloc == SROWS - 1) {
      #pragma unroll
      for (int q = 0; q < 8; ++q) {
        v4f hv; hv[0] = pp[4*q]; hv[1] = pp[4*q+1]; hv[2] = pp[4*q+2]; hv[3] = pp[4*q+3];
        st4c(&myhalo[256 + k0 + 4 * q], hv);
      }
    }
    drain_all();
    __syncthreads();
    if (tid == 0)
      __hip_atomic_fetch_add(&cntP[b * NIT1 + it], 1, __ATOMIC_RELAXED,
                             __HIP_MEMORY_SCOPE_AGENT);
  }

  float* oB = out + gbase;
  #pragma unroll
  for (int i = 0; i < 32; ++i) oB[i] = uu[i];
}

extern "C" void kernel_launch(void* const* d_in, const int* in_sizes, int n_in,
                              void* d_out, int out_size, void* d_ws, size_t ws_size,
                              hipStream_t stream) {
  const float* alpha = (const float*)d_in[0];   // (64, 257, 257) fp32
  const float* frhs  = (const float*)d_in[1];   // (256, 256) fp32
  float* out = (float*)d_out;                   // (64, 256, 256) fp32

  char* ws = (char*)d_ws;
  int*   Z    = (int*)ws;                               // 5 int arrays [64][301]
  float* av   = (float*)(ws + (size_t)5 * SARR * 4);
  float* bv   = (float*)(ws + (size_t)6 * SARR * 4);
  size_t ZR   = ((size_t)7 * SARR * 4 + 4095) & ~(size_t)4095;
  float* halo  = (float*)(ws + ZR);                     // 2 MB
  float* pbuf  = (float*)(ws + ZR + (size_t)NBLK * 512 * 4);
  float* apbuf = pbuf  + (size_t)NBATCH * MM * MM;      // 16 MB each
  float* rbuf  = apbuf + (size_t)NBATCH * MM * MM;

  int nz = 5 * SARR;
  hipLaunchKernelGGL(init_ws_kernel, dim3((nz + 255) / 256), dim3(256), 0, stream,
                     Z, nz);
  hipLaunchKernelGGL(cg_kernel, dim3(NBLK), dim3(TPB), 0, stream,
                     alpha, frhs, out, Z, av, bv, halo, pbuf, apbuf, rbuf);
}